// Round 9
// baseline (187.170 us; speedup 1.0000x reference)
//
#include <hip/hip_runtime.h>
#include <math.h>

#define BB 16
#define NN 4096
#define DD 128
#define KK 1024
#define NPTS (BB*NN)

typedef _Float16 half8 __attribute__((ext_vector_type(8)));
typedef float f32x16 __attribute__((ext_vector_type(16)));

static __device__ __forceinline__ uint pack2(float a, float b) {
    _Float16 ha = (_Float16)a, hb = (_Float16)b;
    unsigned short ua = __builtin_bit_cast(unsigned short, ha);
    unsigned short ub = __builtin_bit_cast(unsigned short, hb);
    return (uint)ua | ((uint)ub << 16);
}

typedef __attribute__((address_space(1))) const void as1_void;
typedef __attribute__((address_space(3))) void as3_void;
static __device__ __forceinline__ void gld16(const void* g, void* l) {
    // async global->LDS, 16B/lane; LDS dest = uniform base + lane*16 (HW rule)
    __builtin_amdgcn_global_load_lds((as1_void*)g, (as3_void*)l, 16, 0, 0);
}

// counted waits + raw barrier (loads stay in flight ACROSS barriers — T3/T4)
#define VMWAIT4 asm volatile("s_waitcnt vmcnt(4)" ::: "memory")
#define VMWAIT2 asm volatile("s_waitcnt vmcnt(2)" ::: "memory")
#define VMWAIT0 asm volatile("s_waitcnt vmcnt(0)" ::: "memory")
#define LGKM0   asm volatile("s_waitcnt lgkmcnt(0)" ::: "memory")
#define RBARRIER do { __builtin_amdgcn_s_barrier(); asm volatile("" ::: "memory"); } while (0)
#define SCHEDB  __builtin_amdgcn_sched_barrier(0)

// ---------------- kernel 0a: centroid squared norms (wave per row, double shfl reduce) ----------------
__global__ void cnorm_kernel(const float* __restrict__ c, float* __restrict__ cnorm) {
    const int w = threadIdx.x >> 6, lane = threadIdx.x & 63;
    const int row = blockIdx.x * 4 + w;
    float2 v = ((const float2*)(c + (size_t)row * DD))[lane];
    double s = (double)v.x * v.x + (double)v.y * v.y;
#pragma unroll
    for (int m = 1; m < 64; m <<= 1) s += __shfl_xor(s, m);
    if (lane == 0) cnorm[row] = (float)s;
}

// ---------------- kernel 0b: pre-permute centroids into per-lane B-fragment order ----------------
// Fragment (nt, c, lane) = cent row (nt*32 + (lane&31)), d in [c*16+(lane>>5)*8, +8),
// split into fp16 hi + (lo*1024), packed as uint4 (HW-verified layout, R3-R8 pass).
__global__ void cfrag_kernel(const float* __restrict__ cent,
                             uint4* __restrict__ cfh, uint4* __restrict__ cfl) {
    const int gid = blockIdx.x * 256 + threadIdx.x;   // [0, 32*8*64)
    const int nt = gid >> 9;
    const int c = (gid >> 6) & 7;
    const int lane = gid & 63;
    const int row = nt * 32 + (lane & 31);
    const int d0 = c * 16 + (lane >> 5) * 8;
    const float* src = cent + (size_t)row * DD + d0;
    float v[8];
#pragma unroll
    for (int i = 0; i < 8; ++i) v[i] = src[i];
    float lo[8];
#pragma unroll
    for (int i = 0; i < 8; ++i) {
        _Float16 h = (_Float16)v[i];
        lo[i] = (v[i] - (float)h) * 1024.f;
    }
    uint4 h4, l4;
    h4.x = pack2(v[0], v[1]); h4.y = pack2(v[2], v[3]);
    h4.z = pack2(v[4], v[5]); h4.w = pack2(v[6], v[7]);
    l4.x = pack2(lo[0], lo[1]); l4.y = pack2(lo[2], lo[3]);
    l4.z = pack2(lo[4], lo[5]); l4.w = pack2(lo[6], lo[7]);
    cfh[gid] = h4;
    cfl[gid] = l4;
}

// ---------------- kernel 1: nearest-centroid, split-K counted-vmcnt ring pipeline ----------------
// 1024 blocks x 4 waves; block = (pblk = bid>>1, kh = bid&1). Wave w owns rows
// [pblk*128+w*32, +32); block scans centroid tiles [kh*16, kh*16+16) (16 tiles,
// 32 half-tile phases). R7's proven ring protocol: 4-slot LDS ring, stage s ->
// slot s&3; phase h reads stage h, issues stage h+3, ends with lgkm0 +
// vmcnt(4) + raw s_barrier (tail 4->2->0). 3 blocks/CU resident (split-K grid)
// -> 3 independent barrier-groups per SIMD hide each other's LDS/MFMA bursts.
__launch_bounds__(256, 3)
__global__ void assign_mfma6(const float* __restrict__ x,
                             const uint4* __restrict__ cfh, const uint4* __restrict__ cfl,
                             const float* __restrict__ cn,
                             float* __restrict__ bestv, int* __restrict__ bkv,
                             float* __restrict__ xn_arr) {
    __shared__ uint4 ring[4][8][64];   // [slot][frag-row: 0-3 hi, 4-7 lo][lane]
    __shared__ float cnS[KK / 2];

    const int tid = threadIdx.x;
    const int lane = tid & 63;
    const int w = tid >> 6;
    const int l31 = lane & 31;
    const int lh = lane >> 5;
    const int kh = blockIdx.x & 1;
    const int pblk = blockIdx.x >> 1;
    const int p0 = pblk * 128 + w * 32;
    // this half's fragment base: tiles [kh*16, +16) -> frag-rows offset kh*16*8
    const uint4* cfhB = cfh + (size_t)kh * 16 * 8 * 64;
    const uint4* cflB = cfl + (size_t)kh * 16 * 8 * 64;

    // A fragments (x rows) + per-row ||x||^2 (identical numerics to R3-R8)
    half8 ahi[8], alo[8];
    float xs = 0.f;
    const float4* xrow = (const float4*)(x + (size_t)(p0 + l31) * DD);
#pragma unroll
    for (int c = 0; c < 8; ++c) {
        float4 v0 = xrow[c * 4 + lh * 2];
        float4 v1 = xrow[c * 4 + lh * 2 + 1];
        float vv[8] = {v0.x, v0.y, v0.z, v0.w, v1.x, v1.y, v1.z, v1.w};
#pragma unroll
        for (int i = 0; i < 8; ++i) {
            _Float16 h = (_Float16)vv[i];
            ahi[c][i] = h;
            alo[c][i] = (_Float16)((vv[i] - (float)h) * 1024.f);
            xs = fmaf(vv[i], vv[i], xs);
        }
    }
    xs += __shfl_xor(xs, 32);   // lane l now has ||row l31||^2

    // this half's cn -> LDS (512 floats)
    ((float2*)cnS)[tid] = ((const float2*)(cn + kh * (KK / 2)))[tid];

    SCHEDB;   // pin: x/cn loads retire above; gld16 issue below (exact vmcnt ledger)

    // prologue: issue stages 0,1,2 (2 gld16 per wave each)
#pragma unroll
    for (int s = 0; s < 3; ++s) {
        const int snt = s >> 1, sh = s & 1;
        gld16(cfhB + ((size_t)(snt * 8 + sh * 4 + w)) * 64 + lane, &ring[s][w][0]);
        gld16(cflB + ((size_t)(snt * 8 + sh * 4 + w)) * 64 + lane, &ring[s][w + 4][0]);
    }

    float best[16];
    int bk[16];
#pragma unroll
    for (int r = 0; r < 16; ++r) { best[r] = INFINITY; bk[r] = 0; }

    VMWAIT4;    // stage 0 landed ({1,2} = 4 loads outstanding)
    LGKM0;      // own cnS ds_write done
    RBARRIER;   // all waves: stage 0 + cnS visible
    SCHEDB;

#define MFMA3(C, BH, BL)                                                            \
    hh  = __builtin_amdgcn_mfma_f32_32x32x16_f16(ahi[C], __builtin_bit_cast(half8, BH), hh, 0, 0, 0);  \
    cr0 = __builtin_amdgcn_mfma_f32_32x32x16_f16(ahi[C], __builtin_bit_cast(half8, BL), cr0, 0, 0, 0); \
    cr1 = __builtin_amdgcn_mfma_f32_32x32x16_f16(alo[C], __builtin_bit_cast(half8, BH), cr1, 0, 0, 0);

#define DO_PHASE(HALF, NT, SSTAGE, DOSTAGE)                                         \
    {                                                                               \
        const int slot_ = (2 * (NT) + (HALF)) & 3;                                  \
        uint4 bh0 = ring[slot_][0][lane], bh1 = ring[slot_][1][lane];               \
        uint4 bh2 = ring[slot_][2][lane], bh3 = ring[slot_][3][lane];               \
        uint4 bl0 = ring[slot_][4][lane], bl1 = ring[slot_][5][lane];               \
        uint4 bl2 = ring[slot_][6][lane], bl3 = ring[slot_][7][lane];               \
        if (DOSTAGE) {                                                              \
            const int s_ = (SSTAGE);                                                \
            const int snt_ = s_ >> 1, sh_ = s_ & 1, ss_ = s_ & 3;                   \
            gld16(cfhB + ((size_t)(snt_ * 8 + sh_ * 4 + w)) * 64 + lane, &ring[ss_][w][0]);     \
            gld16(cflB + ((size_t)(snt_ * 8 + sh_ * 4 + w)) * 64 + lane, &ring[ss_][w + 4][0]); \
        }                                                                           \
        __builtin_amdgcn_s_setprio(1);                                              \
        MFMA3((HALF)*4 + 0, bh0, bl0)                                               \
        MFMA3((HALF)*4 + 1, bh1, bl1)                                               \
        MFMA3((HALF)*4 + 2, bh2, bl2)                                               \
        MFMA3((HALF)*4 + 3, bh3, bl3)                                               \
        __builtin_amdgcn_s_setprio(0);                                              \
    }

#define EPILOGUE(NT)                                                                \
    {                                                                               \
        const float cnv = cnS[(NT) * 32 + l31];                                     \
        const int kcur = (kh * 16 + (NT)) * 32 + l31;                               \
        _Pragma("unroll")                                                           \
        for (int r = 0; r < 16; ++r) {                                              \
            float v = cnv - 2.f * hh[r] - 0.001953125f * (cr0[r] + cr1[r]);         \
            if (v < best[r]) { best[r] = v; bk[r] = kcur; }                         \
        }                                                                           \
    }

#pragma unroll 1
    for (int nt = 0; nt < 14; ++nt) {
        f32x16 hh, cr0, cr1;
#pragma unroll
        for (int i = 0; i < 16; ++i) { hh[i] = 0.f; cr0[i] = 0.f; cr1[i] = 0.f; }
        DO_PHASE(0, nt, 2 * nt + 3, 1)
        VMWAIT4; RBARRIER; SCHEDB;
        DO_PHASE(1, nt, 2 * nt + 4, 1)
        EPILOGUE(nt)
        VMWAIT4; RBARRIER; SCHEDB;
    }
    {   // nt = 14: stage 31 is the last issue; drain schedule 4 -> 2
        f32x16 hh, cr0, cr1;
#pragma unroll
        for (int i = 0; i < 16; ++i) { hh[i] = 0.f; cr0[i] = 0.f; cr1[i] = 0.f; }
        DO_PHASE(0, 14, 31, 1)
        VMWAIT4; RBARRIER; SCHEDB;
        DO_PHASE(1, 14, 0, 0)
        EPILOGUE(14)
        VMWAIT2; RBARRIER; SCHEDB;
    }
    {   // nt = 15: no more staging; 2 -> 0 -> done
        f32x16 hh, cr0, cr1;
#pragma unroll
        for (int i = 0; i < 16; ++i) { hh[i] = 0.f; cr0[i] = 0.f; cr1[i] = 0.f; }
        DO_PHASE(0, 15, 0, 0)
        VMWAIT0; RBARRIER; SCHEDB;
        DO_PHASE(1, 15, 0, 0)
        EPILOGUE(15)
    }
#undef DO_PHASE
#undef MFMA3
#undef EPILOGUE

    // cross-lane argmin over the 32 centroid columns (masks < 32 stay in half-wave)
#pragma unroll
    for (int r = 0; r < 16; ++r) {
        float bv = best[r]; int bi = bk[r];
#pragma unroll
        for (int m = 1; m < 32; m <<= 1) {
            float ov = __shfl_xor(bv, m);
            int oi = __shfl_xor(bi, m);
            if (ov < bv || (ov == bv && oi < bi)) { bv = ov; bi = oi; }
        }
        best[r] = bv; bk[r] = bi;
    }

    // gather ||x||^2 for this half's output rows (static shfl indices, all lanes)
    float xnv[16];
#pragma unroll
    for (int r = 0; r < 16; ++r)
        xnv[r] = __shfl(xs, (r & 3) + 8 * (r >> 2) + 4 * lh);

    if (l31 == 0) {
#pragma unroll
        for (int r = 0; r < 16; ++r) {
            int m = (r & 3) + 8 * (r >> 2) + 4 * lh;   // D-layout row (HW-verified)
            int p = p0 + m;
            bestv[(size_t)kh * NPTS + p] = best[r];    // pre-xn partial min
            bkv[(size_t)kh * NPTS + p] = bk[r];
            if (kh == 0) xn_arr[p] = xnv[r];
        }
    }
}

// ---------------- kernel 2: merge halves + per-batch stats + histogram + normalize ----------------
__global__ void finalize_kernel(const float* __restrict__ bestv, const int* __restrict__ bkv,
                                const float* __restrict__ xn_arr,
                                const float* __restrict__ weights, float* __restrict__ out) {
    __shared__ float dS[NN];      // merged min distances
    __shared__ int   bkS[NN];     // merged argmin
    __shared__ float red[1024];
    __shared__ int hist[KK];
    __shared__ float bc[2];       // mean, thr
    const int b = blockIdx.x;
    const int tid = threadIdx.x;

    // merge the two k-halves (strict <: half-0 ks all smaller -> numpy first-min),
    // then sq = xn + best, d = sqrt(max(sq,0))  — exactly R7's arithmetic order.
    float s = 0.f;
#pragma unroll
    for (int j = 0; j < NN / 1024; ++j) {
        int i = tid + 1024 * j;
        size_t gi = (size_t)b * NN + i;
        float b0 = bestv[gi], b1 = bestv[NPTS + gi];
        int k0 = bkv[gi], k1 = bkv[NPTS + gi];
        float bm = b0; int km = k0;
        if (b1 < bm) { bm = b1; km = k1; }
        float d = sqrtf(fmaxf(xn_arr[gi] + bm, 0.f));
        dS[i] = d; bkS[i] = km;
        s += d;
    }

    // pass A: mean (two-pass std to match numpy numerics)
    red[tid] = s;
    __syncthreads();
    for (int off = 512; off > 0; off >>= 1) {
        if (tid < off) red[tid] += red[tid + off];
        __syncthreads();
    }
    if (tid == 0) bc[0] = red[0] / (float)NN;
    __syncthreads();
    const float mean = bc[0];

    // pass B: sum of squared deviations -> thr = mean + std(ddof=1)
    float ss = 0.f;
#pragma unroll
    for (int j = 0; j < NN / 1024; ++j) {
        float v = dS[tid + 1024 * j] - mean;
        ss += v * v;
    }
    red[tid] = ss;
    __syncthreads();
    for (int off = 512; off > 0; off >>= 1) {
        if (tid < off) red[tid] += red[tid + off];
        __syncthreads();
    }
    if (tid == 0) bc[1] = mean + sqrtf(red[0] / (float)(NN - 1));

    // histogram of masked assignments
    hist[tid] = 0;
    __syncthreads();
    const float thr = bc[1];
#pragma unroll
    for (int j = 0; j < NN / 1024; ++j) {
        int i = tid + 1024 * j;
        if (dS[i] < thr) atomicAdd(&hist[bkS[i]], 1);
    }
    __syncthreads();

    // asmk = counts*weights; L2-normalize the row (one k per thread)
    const float a = (float)hist[tid] * weights[tid];
    red[tid] = a * a;
    __syncthreads();
    for (int off = 512; off > 0; off >>= 1) {
        if (tid < off) red[tid] += red[tid + off];
        __syncthreads();
    }
    const float norm = sqrtf(red[0]);
    const float scale = 1.f / fmaxf(norm, 1e-12f);
    out[(size_t)b * KK + tid] = a * scale;
}

extern "C" void kernel_launch(void* const* d_in, const int* in_sizes, int n_in,
                              void* d_out, int out_size, void* d_ws, size_t ws_size,
                              hipStream_t stream) {
    const float* x = (const float*)d_in[0];
    const float* cent = (const float*)d_in[1];
    const float* weights = (const float*)d_in[2];
    float* out = (float*)d_out;

    char* ws = (char*)d_ws;
    float* bestv  = (float*)(ws + 0);          // [2][NPTS]  512 KB
    int*   bkv    = (int*)  (ws + 524288);     // [2][NPTS]  512 KB
    float* xn_arr = (float*)(ws + 1048576);    // [NPTS]     256 KB
    float* cn     = (float*)(ws + 1310720);    // [KK]         4 KB
    uint4* cfh    = (uint4*)(ws + 1314816);    // 256 KB
    uint4* cfl    = (uint4*)(ws + 1576960);    // 256 KB

    cnorm_kernel<<<KK / 4, 256, 0, stream>>>(cent, cn);
    cfrag_kernel<<<64, 256, 0, stream>>>(cent, cfh, cfl);
    assign_mfma6<<<NPTS / 64, 256, 0, stream>>>(x, cfh, cfl, cn, bestv, bkv, xn_arr);
    finalize_kernel<<<BB, 1024, 0, stream>>>(bestv, bkv, xn_arr, weights, out);
}

// Round 10
// 84.758 us; speedup vs baseline: 2.2083x; 2.2083x over previous
//
#include <hip/hip_runtime.h>
#include <math.h>

#define BB 16
#define NN 4096
#define DD 128
#define KK 1024
#define NPTS (BB*NN)

typedef _Float16 half8 __attribute__((ext_vector_type(8)));
typedef float f32x16 __attribute__((ext_vector_type(16)));

static __device__ __forceinline__ uint pack2(float a, float b) {
    _Float16 ha = (_Float16)a, hb = (_Float16)b;
    unsigned short ua = __builtin_bit_cast(unsigned short, ha);
    unsigned short ub = __builtin_bit_cast(unsigned short, hb);
    return (uint)ua | ((uint)ub << 16);
}

typedef __attribute__((address_space(1))) const void as1_void;
typedef __attribute__((address_space(3))) void as3_void;
static __device__ __forceinline__ void gld16(const void* g, void* l) {
    // async global->LDS, 16B/lane; LDS dest = uniform base + lane*16 (HW rule)
    __builtin_amdgcn_global_load_lds((as1_void*)g, (as3_void*)l, 16, 0, 0);
}

// counted waits + raw barrier (loads stay in flight ACROSS barriers — T3/T4)
#define VMWAIT4 asm volatile("s_waitcnt vmcnt(4)" ::: "memory")
#define VMWAIT2 asm volatile("s_waitcnt vmcnt(2)" ::: "memory")
#define VMWAIT0 asm volatile("s_waitcnt vmcnt(0)" ::: "memory")
#define LGKM0   asm volatile("s_waitcnt lgkmcnt(0)" ::: "memory")
#define RBARRIER do { __builtin_amdgcn_s_barrier(); asm volatile("" ::: "memory"); } while (0)
#define SCHEDB  __builtin_amdgcn_sched_barrier(0)

// ---------------- kernel 0a: centroid squared norms (wave per row, double shfl reduce) ----------------
__global__ void cnorm_kernel(const float* __restrict__ c, float* __restrict__ cnorm) {
    const int w = threadIdx.x >> 6, lane = threadIdx.x & 63;
    const int row = blockIdx.x * 4 + w;
    float2 v = ((const float2*)(c + (size_t)row * DD))[lane];
    double s = (double)v.x * v.x + (double)v.y * v.y;
#pragma unroll
    for (int m = 1; m < 64; m <<= 1) s += __shfl_xor(s, m);
    if (lane == 0) cnorm[row] = (float)s;
}

// ---------------- kernel 0b: pre-permute centroids into per-lane B-fragment order ----------------
// Fragment (nt, c, lane) = cent row (nt*32 + (lane&31)), d in [c*16+(lane>>5)*8, +8),
// split into fp16 hi + (lo*1024), packed as uint4 (HW-verified layout, R3-R9 pass).
__global__ void cfrag_kernel(const float* __restrict__ cent,
                             uint4* __restrict__ cfh, uint4* __restrict__ cfl) {
    const int gid = blockIdx.x * 256 + threadIdx.x;   // [0, 32*8*64)
    const int nt = gid >> 9;
    const int c = (gid >> 6) & 7;
    const int lane = gid & 63;
    const int row = nt * 32 + (lane & 31);
    const int d0 = c * 16 + (lane >> 5) * 8;
    const float* src = cent + (size_t)row * DD + d0;
    float v[8];
#pragma unroll
    for (int i = 0; i < 8; ++i) v[i] = src[i];
    float lo[8];
#pragma unroll
    for (int i = 0; i < 8; ++i) {
        _Float16 h = (_Float16)v[i];
        lo[i] = (v[i] - (float)h) * 1024.f;
    }
    uint4 h4, l4;
    h4.x = pack2(v[0], v[1]); h4.y = pack2(v[2], v[3]);
    h4.z = pack2(v[4], v[5]); h4.w = pack2(v[6], v[7]);
    l4.x = pack2(lo[0], lo[1]); l4.y = pack2(lo[2], lo[3]);
    l4.z = pack2(lo[4], lo[5]); l4.w = pack2(lo[6], lo[7]);
    cfh[gid] = h4;
    cfl[gid] = l4;
}

// ---------------- kernel 1: nearest-centroid, split-K counted-vmcnt ring pipeline ----------------
// 1024 blocks x 4 waves; block = (pblk = bid>>1, kh = bid&1). Wave w owns rows
// [pblk*128+w*32, +32); block scans centroid tiles [kh*16, kh*16+16).
// R7's proven ring protocol (4-slot LDS ring, counted vmcnt, raw barriers).
// launch_bounds (256,2): do NOT cap the allocator (R9's (256,3) forced a 170-reg
// target on a ~210-reg live set -> 125MB/dispatch scratch spill, 3x regression).
// Expected compiled VGPR ~116-124 (R7/R8 identical structure) <= 128 -> HW can
// hold 4 waves/SIMD -> the 1024-block grid supplies 4 resident blocks/CU
// (LDS 34.8KB x 4 = 139KB <= 160KB), i.e. 4 independent barrier-groups whose
// LDS-burst and MFMA-burst phases interleave.
__launch_bounds__(256, 2)
__global__ void assign_mfma6(const float* __restrict__ x,
                             const uint4* __restrict__ cfh, const uint4* __restrict__ cfl,
                             const float* __restrict__ cn,
                             float* __restrict__ bestv, int* __restrict__ bkv,
                             float* __restrict__ xn_arr) {
    __shared__ uint4 ring[4][8][64];   // [slot][frag-row: 0-3 hi, 4-7 lo][lane]
    __shared__ float cnS[KK / 2];

    const int tid = threadIdx.x;
    const int lane = tid & 63;
    const int w = tid >> 6;
    const int l31 = lane & 31;
    const int lh = lane >> 5;
    const int kh = blockIdx.x & 1;
    const int pblk = blockIdx.x >> 1;
    const int p0 = pblk * 128 + w * 32;
    // this half's fragment base: tiles [kh*16, +16) -> frag-rows offset kh*16*8
    const uint4* cfhB = cfh + (size_t)kh * 16 * 8 * 64;
    const uint4* cflB = cfl + (size_t)kh * 16 * 8 * 64;

    // A fragments (x rows) + per-row ||x||^2 (identical numerics to R3-R9)
    half8 ahi[8], alo[8];
    float xs = 0.f;
    const float4* xrow = (const float4*)(x + (size_t)(p0 + l31) * DD);
#pragma unroll
    for (int c = 0; c < 8; ++c) {
        float4 v0 = xrow[c * 4 + lh * 2];
        float4 v1 = xrow[c * 4 + lh * 2 + 1];
        float vv[8] = {v0.x, v0.y, v0.z, v0.w, v1.x, v1.y, v1.z, v1.w};
#pragma unroll
        for (int i = 0; i < 8; ++i) {
            _Float16 h = (_Float16)vv[i];
            ahi[c][i] = h;
            alo[c][i] = (_Float16)((vv[i] - (float)h) * 1024.f);
            xs = fmaf(vv[i], vv[i], xs);
        }
    }
    xs += __shfl_xor(xs, 32);   // lane l now has ||row l31||^2

    // this half's cn -> LDS (512 floats)
    ((float2*)cnS)[tid] = ((const float2*)(cn + kh * (KK / 2)))[tid];

    SCHEDB;   // pin: x/cn loads retire above; gld16 issue below (exact vmcnt ledger)

    // prologue: issue stages 0,1,2 (2 gld16 per wave each)
#pragma unroll
    for (int s = 0; s < 3; ++s) {
        const int snt = s >> 1, sh = s & 1;
        gld16(cfhB + ((size_t)(snt * 8 + sh * 4 + w)) * 64 + lane, &ring[s][w][0]);
        gld16(cflB + ((size_t)(snt * 8 + sh * 4 + w)) * 64 + lane, &ring[s][w + 4][0]);
    }

    float best[16];
    int bk[16];
#pragma unroll
    for (int r = 0; r < 16; ++r) { best[r] = INFINITY; bk[r] = 0; }

    VMWAIT4;    // stage 0 landed ({1,2} = 4 loads outstanding)
    LGKM0;      // own cnS ds_write done
    RBARRIER;   // all waves: stage 0 + cnS visible
    SCHEDB;

#define MFMA3(C, BH, BL)                                                            \
    hh  = __builtin_amdgcn_mfma_f32_32x32x16_f16(ahi[C], __builtin_bit_cast(half8, BH), hh, 0, 0, 0);  \
    cr0 = __builtin_amdgcn_mfma_f32_32x32x16_f16(ahi[C], __builtin_bit_cast(half8, BL), cr0, 0, 0, 0); \
    cr1 = __builtin_amdgcn_mfma_f32_32x32x16_f16(alo[C], __builtin_bit_cast(half8, BH), cr1, 0, 0, 0);

#define DO_PHASE(HALF, NT, SSTAGE, DOSTAGE)                                         \
    {                                                                               \
        const int slot_ = (2 * (NT) + (HALF)) & 3;                                  \
        uint4 bh0 = ring[slot_][0][lane], bh1 = ring[slot_][1][lane];               \
        uint4 bh2 = ring[slot_][2][lane], bh3 = ring[slot_][3][lane];               \
        uint4 bl0 = ring[slot_][4][lane], bl1 = ring[slot_][5][lane];               \
        uint4 bl2 = ring[slot_][6][lane], bl3 = ring[slot_][7][lane];               \
        if (DOSTAGE) {                                                              \
            const int s_ = (SSTAGE);                                                \
            const int snt_ = s_ >> 1, sh_ = s_ & 1, ss_ = s_ & 3;                   \
            gld16(cfhB + ((size_t)(snt_ * 8 + sh_ * 4 + w)) * 64 + lane, &ring[ss_][w][0]);     \
            gld16(cflB + ((size_t)(snt_ * 8 + sh_ * 4 + w)) * 64 + lane, &ring[ss_][w + 4][0]); \
        }                                                                           \
        __builtin_amdgcn_s_setprio(1);                                              \
        MFMA3((HALF)*4 + 0, bh0, bl0)                                               \
        MFMA3((HALF)*4 + 1, bh1, bl1)                                               \
        MFMA3((HALF)*4 + 2, bh2, bl2)                                               \
        MFMA3((HALF)*4 + 3, bh3, bl3)                                               \
        __builtin_amdgcn_s_setprio(0);                                              \
    }

#define EPILOGUE(NT)                                                                \
    {                                                                               \
        const float cnv = cnS[(NT) * 32 + l31];                                     \
        const int kcur = (kh * 16 + (NT)) * 32 + l31;                               \
        _Pragma("unroll")                                                           \
        for (int r = 0; r < 16; ++r) {                                              \
            float v = cnv - 2.f * hh[r] - 0.001953125f * (cr0[r] + cr1[r]);         \
            if (v < best[r]) { best[r] = v; bk[r] = kcur; }                         \
        }                                                                           \
    }

#pragma unroll 1
    for (int nt = 0; nt < 14; ++nt) {
        f32x16 hh, cr0, cr1;
#pragma unroll
        for (int i = 0; i < 16; ++i) { hh[i] = 0.f; cr0[i] = 0.f; cr1[i] = 0.f; }
        DO_PHASE(0, nt, 2 * nt + 3, 1)
        VMWAIT4; RBARRIER; SCHEDB;
        DO_PHASE(1, nt, 2 * nt + 4, 1)
        EPILOGUE(nt)
        VMWAIT4; RBARRIER; SCHEDB;
    }
    {   // nt = 14: stage 31 is the last issue; drain schedule 4 -> 2
        f32x16 hh, cr0, cr1;
#pragma unroll
        for (int i = 0; i < 16; ++i) { hh[i] = 0.f; cr0[i] = 0.f; cr1[i] = 0.f; }
        DO_PHASE(0, 14, 31, 1)
        VMWAIT4; RBARRIER; SCHEDB;
        DO_PHASE(1, 14, 0, 0)
        EPILOGUE(14)
        VMWAIT2; RBARRIER; SCHEDB;
    }
    {   // nt = 15: no more staging; 2 -> 0 -> done
        f32x16 hh, cr0, cr1;
#pragma unroll
        for (int i = 0; i < 16; ++i) { hh[i] = 0.f; cr0[i] = 0.f; cr1[i] = 0.f; }
        DO_PHASE(0, 15, 0, 0)
        VMWAIT0; RBARRIER; SCHEDB;
        DO_PHASE(1, 15, 0, 0)
        EPILOGUE(15)
    }
#undef DO_PHASE
#undef MFMA3
#undef EPILOGUE

    // cross-lane argmin over the 32 centroid columns (masks < 32 stay in half-wave)
#pragma unroll
    for (int r = 0; r < 16; ++r) {
        float bv = best[r]; int bi = bk[r];
#pragma unroll
        for (int m = 1; m < 32; m <<= 1) {
            float ov = __shfl_xor(bv, m);
            int oi = __shfl_xor(bi, m);
            if (ov < bv || (ov == bv && oi < bi)) { bv = ov; bi = oi; }
        }
        best[r] = bv; bk[r] = bi;
    }

    // gather ||x||^2 for this half's output rows (static shfl indices, all lanes)
    float xnv[16];
#pragma unroll
    for (int r = 0; r < 16; ++r)
        xnv[r] = __shfl(xs, (r & 3) + 8 * (r >> 2) + 4 * lh);

    if (l31 == 0) {
#pragma unroll
        for (int r = 0; r < 16; ++r) {
            int m = (r & 3) + 8 * (r >> 2) + 4 * lh;   // D-layout row (HW-verified)
            int p = p0 + m;
            bestv[(size_t)kh * NPTS + p] = best[r];    // pre-xn partial min
            bkv[(size_t)kh * NPTS + p] = bk[r];
            if (kh == 0) xn_arr[p] = xnv[r];
        }
    }
}

// ---------------- kernel 2: merge halves + per-batch stats + histogram + normalize ----------------
__global__ void finalize_kernel(const float* __restrict__ bestv, const int* __restrict__ bkv,
                                const float* __restrict__ xn_arr,
                                const float* __restrict__ weights, float* __restrict__ out) {
    __shared__ float dS[NN];      // merged min distances
    __shared__ int   bkS[NN];     // merged argmin
    __shared__ float red[1024];
    __shared__ int hist[KK];
    __shared__ float bc[2];       // mean, thr
    const int b = blockIdx.x;
    const int tid = threadIdx.x;

    // merge the two k-halves (strict <: half-0 ks all smaller -> numpy first-min),
    // then sq = xn + best, d = sqrt(max(sq,0))  — exactly R7's arithmetic order.
    float s = 0.f;
#pragma unroll
    for (int j = 0; j < NN / 1024; ++j) {
        int i = tid + 1024 * j;
        size_t gi = (size_t)b * NN + i;
        float b0 = bestv[gi], b1 = bestv[NPTS + gi];
        int k0 = bkv[gi], k1 = bkv[NPTS + gi];
        float bm = b0; int km = k0;
        if (b1 < bm) { bm = b1; km = k1; }
        float d = sqrtf(fmaxf(xn_arr[gi] + bm, 0.f));
        dS[i] = d; bkS[i] = km;
        s += d;
    }

    // pass A: mean (two-pass std to match numpy numerics)
    red[tid] = s;
    __syncthreads();
    for (int off = 512; off > 0; off >>= 1) {
        if (tid < off) red[tid] += red[tid + off];
        __syncthreads();
    }
    if (tid == 0) bc[0] = red[0] / (float)NN;
    __syncthreads();
    const float mean = bc[0];

    // pass B: sum of squared deviations -> thr = mean + std(ddof=1)
    float ss = 0.f;
#pragma unroll
    for (int j = 0; j < NN / 1024; ++j) {
        float v = dS[tid + 1024 * j] - mean;
        ss += v * v;
    }
    red[tid] = ss;
    __syncthreads();
    for (int off = 512; off > 0; off >>= 1) {
        if (tid < off) red[tid] += red[tid + off];
        __syncthreads();
    }
    if (tid == 0) bc[1] = mean + sqrtf(red[0] / (float)(NN - 1));

    // histogram of masked assignments
    hist[tid] = 0;
    __syncthreads();
    const float thr = bc[1];
#pragma unroll
    for (int j = 0; j < NN / 1024; ++j) {
        int i = tid + 1024 * j;
        if (dS[i] < thr) atomicAdd(&hist[bkS[i]], 1);
    }
    __syncthreads();

    // asmk = counts*weights; L2-normalize the row (one k per thread)
    const float a = (float)hist[tid] * weights[tid];
    red[tid] = a * a;
    __syncthreads();
    for (int off = 512; off > 0; off >>= 1) {
        if (tid < off) red[tid] += red[tid + off];
        __syncthreads();
    }
    const float norm = sqrtf(red[0]);
    const float scale = 1.f / fmaxf(norm, 1e-12f);
    out[(size_t)b * KK + tid] = a * scale;
}

extern "C" void kernel_launch(void* const* d_in, const int* in_sizes, int n_in,
                              void* d_out, int out_size, void* d_ws, size_t ws_size,
                              hipStream_t stream) {
    const float* x = (const float*)d_in[0];
    const float* cent = (const float*)d_in[1];
    const float* weights = (const float*)d_in[2];
    float* out = (float*)d_out;

    char* ws = (char*)d_ws;
    float* bestv  = (float*)(ws + 0);          // [2][NPTS]  512 KB
    int*   bkv    = (int*)  (ws + 524288);     // [2][NPTS]  512 KB
    float* xn_arr = (float*)(ws + 1048576);    // [NPTS]     256 KB
    float* cn     = (float*)(ws + 1310720);    // [KK]         4 KB
    uint4* cfh    = (uint4*)(ws + 1314816);    // 256 KB
    uint4* cfl    = (uint4*)(ws + 1576960);    // 256 KB

    cnorm_kernel<<<KK / 4, 256, 0, stream>>>(cent, cn);
    cfrag_kernel<<<64, 256, 0, stream>>>(cent, cfh, cfl);
    assign_mfma6<<<NPTS / 64, 256, 0, stream>>>(x, cfh, cfl, cn, bestv, bkv, xn_arr);
    finalize_kernel<<<BB, 1024, 0, stream>>>(bestv, bkv, xn_arr, weights, out);
}

// Round 11
// 76.820 us; speedup vs baseline: 2.4365x; 1.1033x over previous
//
#include <hip/hip_runtime.h>
#include <math.h>

#define BB 16
#define NN 4096
#define DD 128
#define KK 1024
#define NPTS (BB*NN)

typedef _Float16 half8 __attribute__((ext_vector_type(8)));
typedef float f32x16 __attribute__((ext_vector_type(16)));

static __device__ __forceinline__ uint pack2(float a, float b) {
    _Float16 ha = (_Float16)a, hb = (_Float16)b;
    unsigned short ua = __builtin_bit_cast(unsigned short, ha);
    unsigned short ub = __builtin_bit_cast(unsigned short, hb);
    return (uint)ua | ((uint)ub << 16);
}

typedef __attribute__((address_space(1))) const void as1_void;
typedef __attribute__((address_space(3))) void as3_void;
static __device__ __forceinline__ void gld16(const void* g, void* l) {
    // async global->LDS, 16B/lane; LDS dest = uniform base + lane*16 (HW rule)
    __builtin_amdgcn_global_load_lds((as1_void*)g, (as3_void*)l, 16, 0, 0);
}

// counted waits + raw barrier (loads stay in flight ACROSS barriers — T3/T4)
#define VMWAIT4 asm volatile("s_waitcnt vmcnt(4)" ::: "memory")
#define VMWAIT2 asm volatile("s_waitcnt vmcnt(2)" ::: "memory")
#define VMWAIT0 asm volatile("s_waitcnt vmcnt(0)" ::: "memory")
#define LGKM0   asm volatile("s_waitcnt lgkmcnt(0)" ::: "memory")
#define RBARRIER do { __builtin_amdgcn_s_barrier(); asm volatile("" ::: "memory"); } while (0)
#define SCHEDB  __builtin_amdgcn_sched_barrier(0)

// ---------------- kernel 0a: centroid squared norms (wave per row, double shfl reduce) ----------------
__global__ void cnorm_kernel(const float* __restrict__ c, float* __restrict__ cnorm) {
    const int w = threadIdx.x >> 6, lane = threadIdx.x & 63;
    const int row = blockIdx.x * 4 + w;
    float2 v = ((const float2*)(c + (size_t)row * DD))[lane];
    double s = (double)v.x * v.x + (double)v.y * v.y;
#pragma unroll
    for (int m = 1; m < 64; m <<= 1) s += __shfl_xor(s, m);
    if (lane == 0) cnorm[row] = (float)s;
}

// ---------------- kernel 0b: pre-permute centroids into per-lane B-fragment order ----------------
// Fragment (nt, c, lane) = cent row (nt*32 + (lane&31)), d in [c*16+(lane>>5)*8, +8),
// split into fp16 hi + (lo*1024), packed as uint4 (HW-verified layout, R3-R10 pass).
__global__ void cfrag_kernel(const float* __restrict__ cent,
                             uint4* __restrict__ cfh, uint4* __restrict__ cfl) {
    const int gid = blockIdx.x * 256 + threadIdx.x;   // [0, 32*8*64)
    const int nt = gid >> 9;
    const int c = (gid >> 6) & 7;
    const int lane = gid & 63;
    const int row = nt * 32 + (lane & 31);
    const int d0 = c * 16 + (lane >> 5) * 8;
    const float* src = cent + (size_t)row * DD + d0;
    float v[8];
#pragma unroll
    for (int i = 0; i < 8; ++i) v[i] = src[i];
    float lo[8];
#pragma unroll
    for (int i = 0; i < 8; ++i) {
        _Float16 h = (_Float16)v[i];
        lo[i] = (v[i] - (float)h) * 1024.f;
    }
    uint4 h4, l4;
    h4.x = pack2(v[0], v[1]); h4.y = pack2(v[2], v[3]);
    h4.z = pack2(v[4], v[5]); h4.w = pack2(v[6], v[7]);
    l4.x = pack2(lo[0], lo[1]); l4.y = pack2(lo[2], lo[3]);
    l4.z = pack2(lo[4], lo[5]); l4.w = pack2(lo[6], lo[7]);
    cfh[gid] = h4;
    cfl[gid] = l4;
}

// ---------------- kernel 1: nearest-centroid, 8-slot ring + cross-tile register pipeline ----------------
// 512 blocks x 4 waves, full K. Stage = half-tile (8 frag-rows = 8KB), stage s -> slot s&7.
// Tile t (one barrier per tile):
//   [R0 holds stage 2t, read during tile t-1]
//   ds_read stage 2t+1 -> R1 ; SCHEDB   (issued, NOT awaited here)
//   gld16 stage 2t+6            ; SCHEDB
//   MFMA half0 on R0  (zero lgkm dependency -> no stall)
//   ds_read stage 2t+2 -> R0 (next tile) ; SCHEDB
//   gld16 stage 2t+7            ; SCHEDB
//   MFMA half1 on R1  (read latency covered by half0's MFMA issue)
//   epilogue ; lgkm0 ; vmcnt(4) ; s_barrier
// vmcnt ledger: end of tile t -> exactly stages {2t+6,2t+7} (4 loads) outstanding
// => stages <= 2t+5 landed => tile t+1 reads stages 2t+3, 2t+4 with margin.
// Slot-hazard: writes (2t+6,2t+7)&7 vs reads (2t+1,2t+2)&7 -> diffs 4..6 mod 8, disjoint.
// Tail: t=29 no issue, vmcnt(2); t=30 vmcnt(0); t=31 no R0-next read, no barrier.
__launch_bounds__(256, 2)
__global__ void assign_mfma7(const float* __restrict__ x,
                             const uint4* __restrict__ cfh, const uint4* __restrict__ cfl,
                             const float* __restrict__ cn,
                             float* __restrict__ min_d, int* __restrict__ nearest) {
    __shared__ uint4 ring[8][8][64];   // [slot][frag-row: 0-3 hi(c), 4-7 lo(c)][lane]
    __shared__ float cnS[KK];

    const int tid = threadIdx.x;
    const int lane = tid & 63;
    const int w = tid >> 6;
    const int l31 = lane & 31;
    const int lh = lane >> 5;
    const int p0 = blockIdx.x * 128 + w * 32;

#define STAGE_ISSUE(S)                                                              \
    { const int s_ = (S); const int snt_ = s_ >> 1, sh_ = s_ & 1, sl_ = s_ & 7;     \
      gld16(cfh + ((size_t)(snt_ * 8 + sh_ * 4 + w)) * 64 + lane, &ring[sl_][w][0]);     \
      gld16(cfl + ((size_t)(snt_ * 8 + sh_ * 4 + w)) * 64 + lane, &ring[sl_][w + 4][0]); }

    // prologue: issue stages 0..5 FIRST (they fly under the x-load latency)
#pragma unroll
    for (int s = 0; s < 6; ++s) STAGE_ISSUE(s)

    // cn -> LDS (consumed in epilogues; keeps the loop free of global loads)
    ((float4*)cnS)[tid] = ((const float4*)cn)[tid];

    // A fragments (x rows) + per-row ||x||^2 (identical numerics to R3-R10).
    // Building these consumes the x loads -> by VMWAIT4 all 12 gld16 (earlier in
    // the VMEM FIFO) have landed; ledger enters the loop with 0 outstanding.
    half8 ahi[8], alo[8];
    float xs = 0.f;
    const float4* xrow = (const float4*)(x + (size_t)(p0 + l31) * DD);
#pragma unroll
    for (int c = 0; c < 8; ++c) {
        float4 v0 = xrow[c * 4 + lh * 2];
        float4 v1 = xrow[c * 4 + lh * 2 + 1];
        float vv[8] = {v0.x, v0.y, v0.z, v0.w, v1.x, v1.y, v1.z, v1.w};
#pragma unroll
        for (int i = 0; i < 8; ++i) {
            _Float16 h = (_Float16)vv[i];
            ahi[c][i] = h;
            alo[c][i] = (_Float16)((vv[i] - (float)h) * 1024.f);
            xs = fmaf(vv[i], vv[i], xs);
        }
    }
    xs += __shfl_xor(xs, 32);   // lane l now has ||row l31||^2

    float best[16];
    int bk[16];
#pragma unroll
    for (int r = 0; r < 16; ++r) { best[r] = INFINITY; bk[r] = 0; }

    VMWAIT4;    // stages 0..3 landed at minimum (see FIFO note above)
    LGKM0;      // own cnS ds_write done
    RBARRIER;   // all waves: staged data + cnS visible
    SCHEDB;

    // pre-read stage 0 -> R0 (CUR for tile 0's half0)
    uint4 R0[8], R1[8];
#pragma unroll
    for (int j = 0; j < 8; ++j) R0[j] = ring[0][j][lane];
    SCHEDB;

#define MFMA_HALF(HALF, BUF)                                                        \
    __builtin_amdgcn_s_setprio(1);                                                  \
    _Pragma("unroll")                                                               \
    for (int c = 0; c < 4; ++c) {                                                   \
        half8 vbh = __builtin_bit_cast(half8, BUF[c]);                              \
        half8 vbl = __builtin_bit_cast(half8, BUF[4 + c]);                          \
        hh = __builtin_amdgcn_mfma_f32_32x32x16_f16(ahi[(HALF) * 4 + c], vbh, hh, 0, 0, 0); \
        cr = __builtin_amdgcn_mfma_f32_32x32x16_f16(ahi[(HALF) * 4 + c], vbl, cr, 0, 0, 0); \
        cr = __builtin_amdgcn_mfma_f32_32x32x16_f16(alo[(HALF) * 4 + c], vbh, cr, 0, 0, 0); \
    }                                                                               \
    __builtin_amdgcn_s_setprio(0);

#define TILE(NT, DOR0N, DOSTG, WAITSEQ)                                             \
    {                                                                               \
        f32x16 hh, cr;                                                              \
        _Pragma("unroll")                                                           \
        for (int i = 0; i < 16; ++i) { hh[i] = 0.f; cr[i] = 0.f; }                  \
        {   const int s1_ = (2 * (NT) + 1) & 7;                                     \
            _Pragma("unroll")                                                       \
            for (int j = 0; j < 8; ++j) R1[j] = ring[s1_][j][lane]; }               \
        SCHEDB;                                                                     \
        if (DOSTG) STAGE_ISSUE(2 * (NT) + 6)                                        \
        SCHEDB;                                                                     \
        MFMA_HALF(0, R0)                                                            \
        if (DOR0N) {                                                                \
            const int s2_ = (2 * (NT) + 2) & 7;                                     \
            _Pragma("unroll")                                                       \
            for (int j = 0; j < 8; ++j) R0[j] = ring[s2_][j][lane];                 \
        }                                                                           \
        SCHEDB;                                                                     \
        if (DOSTG) STAGE_ISSUE(2 * (NT) + 7)                                        \
        SCHEDB;                                                                     \
        MFMA_HALF(1, R1)                                                            \
        {   const float cnv_ = cnS[(NT) * 32 + l31];                                \
            const int kcur_ = (NT) * 32 + l31;                                      \
            _Pragma("unroll")                                                       \
            for (int r = 0; r < 16; ++r) {                                          \
                float v_ = cnv_ - 2.f * hh[r] - 0.001953125f * cr[r];               \
                if (v_ < best[r]) { best[r] = v_; bk[r] = kcur_; }                  \
            }                                                                       \
        }                                                                           \
        WAITSEQ;                                                                    \
    }

#define W4 do { LGKM0; VMWAIT4; RBARRIER; SCHEDB; } while (0)
#define W2 do { LGKM0; VMWAIT2; RBARRIER; SCHEDB; } while (0)
#define W0 do { LGKM0; VMWAIT0; RBARRIER; SCHEDB; } while (0)
#define WN do { } while (0)

#pragma unroll 1
    for (int t = 0; t < 29; ++t) {
        TILE(t, 1, 1, W4)
    }
    TILE(29, 1, 0, W2)   // no more staging; 62,63 still in flight -> need 61,62: wait to 2
    TILE(30, 1, 0, W0)   // tile 31 reads stage 63: drain fully
    TILE(31, 0, 0, WN)   // last tile: R1 = stage 63; no next-R0 read, no barrier
#undef TILE
#undef MFMA_HALF
#undef STAGE_ISSUE
#undef W4
#undef W2
#undef W0
#undef WN

    // cross-lane argmin over the 32 centroid columns (masks < 32 stay in half-wave)
#pragma unroll
    for (int r = 0; r < 16; ++r) {
        float bv = best[r]; int bi = bk[r];
#pragma unroll
        for (int m = 1; m < 32; m <<= 1) {
            float ov = __shfl_xor(bv, m);
            int oi = __shfl_xor(bi, m);
            if (ov < bv || (ov == bv && oi < bi)) { bv = ov; bi = oi; }
        }
        best[r] = bv; bk[r] = bi;
    }

    // gather ||x||^2 for this half's output rows (static shfl indices, all lanes)
    float xnv[16];
#pragma unroll
    for (int r = 0; r < 16; ++r)
        xnv[r] = __shfl(xs, (r & 3) + 8 * (r >> 2) + 4 * lh);

    if (l31 == 0) {
#pragma unroll
        for (int r = 0; r < 16; ++r) {
            int m = (r & 3) + 8 * (r >> 2) + 4 * lh;   // D-layout row (HW-verified)
            float sq = xnv[r] + best[r];
            min_d[p0 + m] = sqrtf(fmaxf(sq, 0.f));
            nearest[p0 + m] = bk[r];
        }
    }
}

// ---------------- kernel 2: per-batch stats + histogram + normalize (1024 threads) ----------------
__global__ void finalize_kernel(const float* __restrict__ min_d, const int* __restrict__ nearest,
                                const float* __restrict__ weights, float* __restrict__ out) {
    __shared__ float red[1024];
    __shared__ int hist[KK];
    __shared__ float bc[2];  // mean, thr
    const int b = blockIdx.x;
    const int tid = threadIdx.x;
    const float* md = min_d + (size_t)b * NN;
    const int* nr = nearest + (size_t)b * NN;

    // pass A: mean (two-pass std to match numpy numerics)
    float s = 0.f;
#pragma unroll
    for (int j = 0; j < NN / 1024; ++j) s += md[tid + 1024 * j];
    red[tid] = s;
    __syncthreads();
    for (int off = 512; off > 0; off >>= 1) {
        if (tid < off) red[tid] += red[tid + off];
        __syncthreads();
    }
    if (tid == 0) bc[0] = red[0] / (float)NN;
    __syncthreads();
    const float mean = bc[0];

    // pass B: sum of squared deviations -> thr = mean + std(ddof=1)
    float ss = 0.f;
#pragma unroll
    for (int j = 0; j < NN / 1024; ++j) {
        float v = md[tid + 1024 * j] - mean;
        ss += v * v;
    }
    red[tid] = ss;
    __syncthreads();
    for (int off = 512; off > 0; off >>= 1) {
        if (tid < off) red[tid] += red[tid + off];
        __syncthreads();
    }
    if (tid == 0) bc[1] = mean + sqrtf(red[0] / (float)(NN - 1));

    // histogram of masked assignments
    hist[tid] = 0;
    __syncthreads();
    const float thr = bc[1];
#pragma unroll
    for (int j = 0; j < NN / 1024; ++j) {
        int i = tid + 1024 * j;
        if (md[i] < thr) atomicAdd(&hist[nr[i]], 1);
    }
    __syncthreads();

    // asmk = counts*weights; L2-normalize the row (one k per thread)
    const float a = (float)hist[tid] * weights[tid];
    red[tid] = a * a;
    __syncthreads();
    for (int off = 512; off > 0; off >>= 1) {
        if (tid < off) red[tid] += red[tid + off];
        __syncthreads();
    }
    const float norm = sqrtf(red[0]);
    const float scale = 1.f / fmaxf(norm, 1e-12f);
    out[(size_t)b * KK + tid] = a * scale;
}

extern "C" void kernel_launch(void* const* d_in, const int* in_sizes, int n_in,
                              void* d_out, int out_size, void* d_ws, size_t ws_size,
                              hipStream_t stream) {
    const float* x = (const float*)d_in[0];
    const float* cent = (const float*)d_in[1];
    const float* weights = (const float*)d_in[2];
    float* out = (float*)d_out;

    char* ws = (char*)d_ws;
    float* min_d   = (float*)(ws + 0);
    int*   nearest = (int*)  (ws + 262144);
    float* cn      = (float*)(ws + 524288);
    uint4* cfh     = (uint4*)(ws + 528384);
    uint4* cfl     = (uint4*)(ws + 790528);

    cnorm_kernel<<<KK / 4, 256, 0, stream>>>(cent, cn);
    cfrag_kernel<<<64, 256, 0, stream>>>(cent, cfh, cfl);
    assign_mfma7<<<NPTS / 128, 256, 0, stream>>>(x, cfh, cfl, cn, min_d, nearest);
    finalize_kernel<<<BB, 1024, 0, stream>>>(min_d, nearest, weights, out);
}

// Round 12
// 73.364 us; speedup vs baseline: 2.5513x; 1.0471x over previous
//
#include <hip/hip_runtime.h>
#include <math.h>

#define BB 16
#define NN 4096
#define DD 128
#define KK 1024
#define NPTS (BB*NN)

typedef _Float16 half8 __attribute__((ext_vector_type(8)));
typedef float f32x4 __attribute__((ext_vector_type(4)));

static __device__ __forceinline__ uint pack2(float a, float b) {
    _Float16 ha = (_Float16)a, hb = (_Float16)b;
    unsigned short ua = __builtin_bit_cast(unsigned short, ha);
    unsigned short ub = __builtin_bit_cast(unsigned short, hb);
    return (uint)ua | ((uint)ub << 16);
}

typedef __attribute__((address_space(1))) const void as1_void;
typedef __attribute__((address_space(3))) void as3_void;
static __device__ __forceinline__ void gld16(const void* g, void* l) {
    // async global->LDS, 16B/lane; LDS dest = uniform base + lane*16 (HW rule)
    __builtin_amdgcn_global_load_lds((as1_void*)g, (as3_void*)l, 16, 0, 0);
}

// counted waits + raw barrier (loads stay in flight ACROSS barriers — T3/T4)
#define VMWAIT4 asm volatile("s_waitcnt vmcnt(4)" ::: "memory")
#define VMWAIT2 asm volatile("s_waitcnt vmcnt(2)" ::: "memory")
#define VMWAIT0 asm volatile("s_waitcnt vmcnt(0)" ::: "memory")
#define LGKM0   asm volatile("s_waitcnt lgkmcnt(0)" ::: "memory")
#define RBARRIER do { __builtin_amdgcn_s_barrier(); asm volatile("" ::: "memory"); } while (0)
#define SCHEDB  __builtin_amdgcn_sched_barrier(0)

// ---------------- kernel 0a: centroid squared norms (wave per row, double shfl reduce) ----------------
__global__ void cnorm_kernel(const float* __restrict__ c, float* __restrict__ cnorm) {
    const int w = threadIdx.x >> 6, lane = threadIdx.x & 63;
    const int row = blockIdx.x * 4 + w;
    float2 v = ((const float2*)(c + (size_t)row * DD))[lane];
    double s = (double)v.x * v.x + (double)v.y * v.y;
#pragma unroll
    for (int m = 1; m < 64; m <<= 1) s += __shfl_xor(s, m);
    if (lane == 0) cnorm[row] = (float)s;
}

// ---------------- kernel 0b: pre-permute centroids into 16x16x32 B-fragment order ----------------
// Fragment (nt, c, lane) = cent row (nt*16 + (lane&15)), d in [c*32 + (lane>>4)*8, +8),
// split into fp16 hi + (lo*1024), packed as uint4.
// NOTE: any within-operand k-relabeling cancels because A and B use the SAME
// (group,elem)->k convention; the contraction sum is k-permutation-invariant.
__global__ void cfrag_kernel(const float* __restrict__ cent,
                             uint4* __restrict__ cfh, uint4* __restrict__ cfl) {
    const int gid = blockIdx.x * 256 + threadIdx.x;   // [0, 64*4*64) = 16384
    const int nt = gid >> 8;
    const int c = (gid >> 6) & 3;
    const int lane = gid & 63;
    const int row = nt * 16 + (lane & 15);
    const int d0 = c * 32 + (lane >> 4) * 8;
    const float* src = cent + (size_t)row * DD + d0;
    float v[8];
#pragma unroll
    for (int i = 0; i < 8; ++i) v[i] = src[i];
    float lo[8];
#pragma unroll
    for (int i = 0; i < 8; ++i) {
        _Float16 h = (_Float16)v[i];
        lo[i] = (v[i] - (float)h) * 1024.f;
    }
    uint4 h4, l4;
    h4.x = pack2(v[0], v[1]); h4.y = pack2(v[2], v[3]);
    h4.z = pack2(v[4], v[5]); h4.w = pack2(v[6], v[7]);
    l4.x = pack2(lo[0], lo[1]); l4.y = pack2(lo[2], lo[3]);
    l4.z = pack2(lo[4], lo[5]); l4.w = pack2(lo[6], lo[7]);
    cfh[gid] = h4;
    cfl[gid] = l4;
}

// ---------------- kernel 1: nearest-centroid, 16x16x32 MFMA, 4 waves/SIMD ----------------
// 1024 blocks x 4 waves; wave w owns points [block*64 + w*16, +16).
// Per wave: A-frags 8 half8 (32 VGPR), acc hh/cr0/cr1 (12), best/bk (8) ->
// combined regs target <= 128 => 4 waves/SIMD (occupancy quantum 64/128/256, m69).
// 64 phases, one 16-centroid tile each (8KB: 4 hi + 4 lo frag-rows).
// R7's proven ring protocol: 4-slot LDS ring, stage s -> slot s&3; phase t reads
// stage t, issues stage t+3 (2 gld16/wave), 12 MFMA, epilogue, vmcnt(4)+barrier
// (tail 4->2->0). With 4 waves/SIMD the per-wave lgkm stall is TLP-covered.
__launch_bounds__(256, 4)
__global__ void assign_mfma8(const float* __restrict__ x,
                             const uint4* __restrict__ cfh, const uint4* __restrict__ cfl,
                             const float* __restrict__ cn,
                             float* __restrict__ min_d, int* __restrict__ nearest) {
    __shared__ uint4 ring[4][8][64];   // [slot][frag-row: 0-3 hi(c), 4-7 lo(c)][lane]
    __shared__ float cnS[KK];

    const int tid = threadIdx.x;
    const int lane = tid & 63;
    const int w = tid >> 6;
    const int l15 = lane & 15;
    const int lg = lane >> 4;          // k-group 0..3
    const int p0 = blockIdx.x * 64 + w * 16;

#define STAGE_ISSUE(S)                                                              \
    { const int s_ = (S); const int sl_ = s_ & 3;                                   \
      gld16(cfh + ((size_t)s_ * 4 + w) * 64 + lane, &ring[sl_][w][0]);              \
      gld16(cfl + ((size_t)s_ * 4 + w) * 64 + lane, &ring[sl_][w + 4][0]); }

    // prologue: issue stages 0..2 first (fly under the cn/x loads)
#pragma unroll
    for (int s = 0; s < 3; ++s) STAGE_ISSUE(s)

    // cn -> LDS (consumed in epilogues; keeps the loop free of global loads)
    ((float4*)cnS)[tid] = ((const float4*)cn)[tid];

    // A fragments: lane covers row l15, k = c*32 + lg*8 + i (same split as R3-R11)
    half8 ahi[4], alo[4];
    float xs = 0.f;
    const float4* xrow = (const float4*)(x + (size_t)(p0 + l15) * DD);
#pragma unroll
    for (int c = 0; c < 4; ++c) {
        float4 v0 = xrow[c * 8 + lg * 2];
        float4 v1 = xrow[c * 8 + lg * 2 + 1];
        float vv[8] = {v0.x, v0.y, v0.z, v0.w, v1.x, v1.y, v1.z, v1.w};
#pragma unroll
        for (int i = 0; i < 8; ++i) {
            _Float16 h = (_Float16)vv[i];
            ahi[c][i] = h;
            alo[c][i] = (_Float16)((vv[i] - (float)h) * 1024.f);
            xs = fmaf(vv[i], vv[i], xs);
        }
    }
    // lanes {l15, l15+16, l15+32, l15+48} hold disjoint k-quarters of row l15
    xs += __shfl_xor(xs, 16);
    xs += __shfl_xor(xs, 32);          // every lane: ||x_{l15}||^2

    float best[4];
    int bk[4];
#pragma unroll
    for (int r = 0; r < 4; ++r) { best[r] = INFINITY; bk[r] = 0; }

    VMWAIT4;    // x/cn consumption drained older gld16s; stage 0 landed
    LGKM0;      // own cnS ds_write done
    RBARRIER;   // all waves: stage 0 + cnS visible
    SCHEDB;

#define DO_PHASE(NT, SST, DOSTG, WAITSEQ)                                           \
    {                                                                               \
        const int sl_ = (NT) & 3;                                                   \
        uint4 bh0 = ring[sl_][0][lane], bh1 = ring[sl_][1][lane];                   \
        uint4 bh2 = ring[sl_][2][lane], bh3 = ring[sl_][3][lane];                   \
        uint4 bl0 = ring[sl_][4][lane], bl1 = ring[sl_][5][lane];                   \
        uint4 bl2 = ring[sl_][6][lane], bl3 = ring[sl_][7][lane];                   \
        if (DOSTG) STAGE_ISSUE(SST)                                                 \
        f32x4 hh, cr0, cr1;                                                         \
        _Pragma("unroll")                                                           \
        for (int i = 0; i < 4; ++i) { hh[i] = 0.f; cr0[i] = 0.f; cr1[i] = 0.f; }    \
        __builtin_amdgcn_s_setprio(1);                                              \
        hh  = __builtin_amdgcn_mfma_f32_16x16x32_f16(ahi[0], __builtin_bit_cast(half8, bh0), hh, 0, 0, 0);  \
        cr0 = __builtin_amdgcn_mfma_f32_16x16x32_f16(ahi[0], __builtin_bit_cast(half8, bl0), cr0, 0, 0, 0); \
        cr1 = __builtin_amdgcn_mfma_f32_16x16x32_f16(alo[0], __builtin_bit_cast(half8, bh0), cr1, 0, 0, 0); \
        hh  = __builtin_amdgcn_mfma_f32_16x16x32_f16(ahi[1], __builtin_bit_cast(half8, bh1), hh, 0, 0, 0);  \
        cr0 = __builtin_amdgcn_mfma_f32_16x16x32_f16(ahi[1], __builtin_bit_cast(half8, bl1), cr0, 0, 0, 0); \
        cr1 = __builtin_amdgcn_mfma_f32_16x16x32_f16(alo[1], __builtin_bit_cast(half8, bh1), cr1, 0, 0, 0); \
        hh  = __builtin_amdgcn_mfma_f32_16x16x32_f16(ahi[2], __builtin_bit_cast(half8, bh2), hh, 0, 0, 0);  \
        cr0 = __builtin_amdgcn_mfma_f32_16x16x32_f16(ahi[2], __builtin_bit_cast(half8, bl2), cr0, 0, 0, 0); \
        cr1 = __builtin_amdgcn_mfma_f32_16x16x32_f16(alo[2], __builtin_bit_cast(half8, bh2), cr1, 0, 0, 0); \
        hh  = __builtin_amdgcn_mfma_f32_16x16x32_f16(ahi[3], __builtin_bit_cast(half8, bh3), hh, 0, 0, 0);  \
        cr0 = __builtin_amdgcn_mfma_f32_16x16x32_f16(ahi[3], __builtin_bit_cast(half8, bl3), cr0, 0, 0, 0); \
        cr1 = __builtin_amdgcn_mfma_f32_16x16x32_f16(alo[3], __builtin_bit_cast(half8, bh3), cr1, 0, 0, 0); \
        __builtin_amdgcn_s_setprio(0);                                              \
        {   const float cnv_ = cnS[(NT) * 16 + l15];                                \
            const int kcur_ = (NT) * 16 + l15;                                      \
            _Pragma("unroll")                                                       \
            for (int r = 0; r < 4; ++r) {                                           \
                float v_ = cnv_ - 2.f * hh[r] - 0.001953125f * (cr0[r] + cr1[r]);   \
                if (v_ < best[r]) { best[r] = v_; bk[r] = kcur_; }                  \
            }                                                                       \
        }                                                                           \
        WAITSEQ;                                                                    \
    }

#define W4 do { VMWAIT4; RBARRIER; SCHEDB; } while (0)
#define W2 do { VMWAIT2; RBARRIER; SCHEDB; } while (0)
#define W0 do { VMWAIT0; RBARRIER; SCHEDB; } while (0)
#define WN do { } while (0)

#pragma unroll 1
    for (int t = 0; t < 61; ++t) {
        DO_PHASE(t, t + 3, 1, W4)
    }
    DO_PHASE(61, 0, 0, W2)   // outstanding {62,63} -> wait to 2: stage 62 landed
    DO_PHASE(62, 0, 0, W0)   // drain: stage 63 landed
    DO_PHASE(63, 0, 0, WN)   // last tile, no barrier
#undef DO_PHASE
#undef STAGE_ISSUE
#undef W4
#undef W2
#undef W0
#undef WN

    // argmin across the 16 centroid-columns within each 16-lane group
    // (masks < 16 keep lg fixed); numpy tie-break: smaller k
#pragma unroll
    for (int r = 0; r < 4; ++r) {
        float bv = best[r]; int bi = bk[r];
#pragma unroll
        for (int m = 1; m < 16; m <<= 1) {
            float ov = __shfl_xor(bv, m);
            int oi = __shfl_xor(bi, m);
            if (ov < bv || (ov == bv && oi < bi)) { bv = ov; bi = oi; }
        }
        best[r] = bv; bk[r] = bi;
    }

    // D layout (m89-verified): col = lane&15, row = (lane>>4)*4 + r
    float xnv[4];
#pragma unroll
    for (int r = 0; r < 4; ++r)
        xnv[r] = __shfl(xs, lg * 4 + r);   // xs of point (lg*4+r) lives in lane (lg*4+r)

    if (l15 == 0) {
#pragma unroll
        for (int r = 0; r < 4; ++r) {
            int m = lg * 4 + r;
            float sq = xnv[r] + best[r];
            min_d[p0 + m] = sqrtf(fmaxf(sq, 0.f));
            nearest[p0 + m] = bk[r];
        }
    }
}

// ---------------- kernel 2: per-batch stats + histogram + normalize (1024 threads) ----------------
__global__ void finalize_kernel(const float* __restrict__ min_d, const int* __restrict__ nearest,
                                const float* __restrict__ weights, float* __restrict__ out) {
    __shared__ float red[1024];
    __shared__ int hist[KK];
    __shared__ float bc[2];  // mean, thr
    const int b = blockIdx.x;
    const int tid = threadIdx.x;
    const float* md = min_d + (size_t)b * NN;
    const int* nr = nearest + (size_t)b * NN;

    // pass A: mean (two-pass std to match numpy numerics)
    float s = 0.f;
#pragma unroll
    for (int j = 0; j < NN / 1024; ++j) s += md[tid + 1024 * j];
    red[tid] = s;
    __syncthreads();
    for (int off = 512; off > 0; off >>= 1) {
        if (tid < off) red[tid] += red[tid + off];
        __syncthreads();
    }
    if (tid == 0) bc[0] = red[0] / (float)NN;
    __syncthreads();
    const float mean = bc[0];

    // pass B: sum of squared deviations -> thr = mean + std(ddof=1)
    float ss = 0.f;
#pragma unroll
    for (int j = 0; j < NN / 1024; ++j) {
        float v = md[tid + 1024 * j] - mean;
        ss += v * v;
    }
    red[tid] = ss;
    __syncthreads();
    for (int off = 512; off > 0; off >>= 1) {
        if (tid < off) red[tid] += red[tid + off];
        __syncthreads();
    }
    if (tid == 0) bc[1] = mean + sqrtf(red[0] / (float)(NN - 1));

    // histogram of masked assignments
    hist[tid] = 0;
    __syncthreads();
    const float thr = bc[1];
#pragma unroll
    for (int j = 0; j < NN / 1024; ++j) {
        int i = tid + 1024 * j;
        if (md[i] < thr) atomicAdd(&hist[nr[i]], 1);
    }
    __syncthreads();

    // asmk = counts*weights; L2-normalize the row (one k per thread)
    const float a = (float)hist[tid] * weights[tid];
    red[tid] = a * a;
    __syncthreads();
    for (int off = 512; off > 0; off >>= 1) {
        if (tid < off) red[tid] += red[tid + off];
        __syncthreads();
    }
    const float norm = sqrtf(red[0]);
    const float scale = 1.f / fmaxf(norm, 1e-12f);
    out[(size_t)b * KK + tid] = a * scale;
}

extern "C" void kernel_launch(void* const* d_in, const int* in_sizes, int n_in,
                              void* d_out, int out_size, void* d_ws, size_t ws_size,
                              hipStream_t stream) {
    const float* x = (const float*)d_in[0];
    const float* cent = (const float*)d_in[1];
    const float* weights = (const float*)d_in[2];
    float* out = (float*)d_out;

    char* ws = (char*)d_ws;
    float* min_d   = (float*)(ws + 0);
    int*   nearest = (int*)  (ws + 262144);
    float* cn      = (float*)(ws + 524288);
    uint4* cfh     = (uint4*)(ws + 528384);
    uint4* cfl     = (uint4*)(ws + 790528);

    cnorm_kernel<<<KK / 4, 256, 0, stream>>>(cent, cn);
    cfrag_kernel<<<64, 256, 0, stream>>>(cent, cfh, cfl);
    assign_mfma8<<<NPTS / 64, 256, 0, stream>>>(x, cfh, cfl, cn, min_d, nearest);
    finalize_kernel<<<BB, 1024, 0, stream>>>(min_d, nearest, weights, out);
}